// Round 1
// baseline (2826.708 us; speedup 1.0000x reference)
//
#include <hip/hip_runtime.h>
#include <math.h>

#define Bn 32
#define Cn 32
#define Ln 16384
#define NF 511      // number of spectrogram frames
#define NB 33       // rfft bins of 64-pt window
#define MAXSEG 512
#define TB 8192     // total spectral bins per batch (sum of nf over segments = L/2)
#define PEN 5.0

// ---------------- sig = x.mean(axis=channels), float32 sequential (numpy axis-0 reduce order)
__global__ void k_sig(const float* __restrict__ x, float* __restrict__ sig) {
    int idx = blockIdx.x * 256 + threadIdx.x;
    if (idx >= Bn * Ln) return;
    int b = idx >> 14;
    int t = idx & (Ln - 1);
    const float* p = x + ((size_t)b * Cn) * Ln + t;
    float a = p[0];
    #pragma unroll
    for (int c = 1; c < Cn; c++) a += p[(size_t)c * Ln];
    sig[idx] = a / 32.0f;
}

// ---------------- frame means: numpy scalar pairwise 8-accumulator pattern, n=64, float32
__global__ void k_fmean(const float* __restrict__ sig, float* __restrict__ fm) {
    int idx = blockIdx.x * 256 + threadIdx.x;
    if (idx >= Bn * NF) return;
    int b = idx / NF, f = idx - b * NF;
    const float* a = sig + b * Ln + f * 32;
    float r[8];
    #pragma unroll
    for (int j = 0; j < 8; j++) r[j] = a[j];
    #pragma unroll
    for (int base = 8; base < 64; base += 8)
        #pragma unroll
        for (int j = 0; j < 8; j++) r[j] += a[base + j];
    float res = ((r[0] + r[1]) + (r[2] + r[3])) + ((r[4] + r[5]) + (r[6] + r[7]));
    fm[idx] = res / 64.0f;
}

// ---------------- feats = log(|rfft(hann * (frame - mean))|^2 + 1e-8), double
__global__ void k_feats(const float* __restrict__ sig, const float* __restrict__ fm,
                        double* __restrict__ feats) {
    __shared__ double v[64], ct[64], stb[64];
    int bf = blockIdx.x;
    int b = bf / NF, f = bf - b * NF;
    int i = threadIdx.x;  // 0..63
    double ang = (2.0 * M_PI * (double)i) / 64.0;
    double sn, cx;
    sincos(ang, &sn, &cx);
    ct[i] = cx; stb[i] = sn;
    int n2 = 2 * i - 63;                       // np.hanning: arange(1-M, M, 2)
    double w = 0.5 + 0.5 * cos((M_PI * (double)n2) / 63.0);
    float m = fm[bf];
    v[i] = (double)(sig[b * Ln + f * 32 + i] - m) * w;   // f32 subtract, f64 window mult
    __syncthreads();
    if (i < NB) {
        double re = 0.0, im = 0.0;
        for (int t = 0; t < 64; t++) {
            int j = (t * i) & 63;
            re += v[t] * ct[j];
            im += v[t] * stb[j];
        }
        double spec = re * re + im * im;
        feats[(size_t)bf * NB + i] = log(spec + 1e-8);
    }
}

// ---------------- cs / cs2 cumsums (sequential double, numpy cumsum order)
__global__ void k_cumsum(const double* __restrict__ feats, double* __restrict__ cs,
                         double* __restrict__ cs2) {
    int idx = blockIdx.x * 256 + threadIdx.x;
    if (idx >= Bn * NB) return;
    int b = idx / NB, d = idx - b * NB;
    const double* fp = feats + (size_t)b * NF * NB + d;
    double* c1 = cs + (size_t)b * 512 * NB + d;
    double* c2 = cs2 + (size_t)b * 512 * NB + d;
    double a1 = 0.0, a2 = 0.0;
    c1[0] = 0.0; c2[0] = 0.0;
    for (int t = 0; t < NF; t++) {
        double vv = fp[(size_t)t * NB];
        a1 += vv;
        a2 += vv * vv;
        c1[(size_t)(t + 1) * NB] = a1;
        c2[(size_t)(t + 1) * NB] = a2;
    }
}

// ---------------- PELT DP, one block per batch, exact numpy semantics in double
__global__ __launch_bounds__(512) void k_pelt(const double* __restrict__ cs,
                                              const double* __restrict__ cs2,
                                              int* __restrict__ prevG) {
    __shared__ double sFc[512];
    __shared__ unsigned short sCand[512], sNew[512], sPrev[512];
    __shared__ double sCt[NB], sCt2[NB];
    __shared__ double wMin[8];
    __shared__ int wIdx[8];
    __shared__ int grpCnt[8], grpOff[8];
    __shared__ int sNcand, sTotal;
    __shared__ double sThr;

    int b = blockIdx.x;
    int tid = threadIdx.x;
    int lane = tid & 63, wv = tid >> 6;
    const double* c1 = cs + (size_t)b * 512 * NB;
    const double* c2 = cs2 + (size_t)b * 512 * NB;

    sPrev[tid] = 0;
    if (tid == 0) { sFc[0] = -PEN; sCand[0] = 0; sNcand = 1; }
    __syncthreads();

    for (int t = 1; t <= NF; t++) {
        if (tid < NB) { sCt[tid] = c1[(size_t)t * NB + tid]; sCt2[tid] = c2[(size_t)t * NB + tid]; }
        __syncthreads();
        int ncand = sNcand;
        double val = 0.0;
        double mv = INFINITY; int mi = 0x7fffffff;
        if (tid < ncand) {
            int cc = sCand[tid];
            double nn = (double)(t - cc);
            const double* p1 = c1 + (size_t)cc * NB;
            const double* p2 = c2 + (size_t)cc * NB;
            // numpy pairwise sum over 33 dims: 8 accumulators + remainder
            double r[8];
            #pragma unroll
            for (int j = 0; j < 8; j++) {
                double ss = sCt[j] - p1[j]; double s2 = sCt2[j] - p2[j];
                r[j] = s2 - ss * ss / nn;
            }
            #pragma unroll
            for (int base = 8; base < 32; base += 8)
                #pragma unroll
                for (int j = 0; j < 8; j++) {
                    int d = base + j;
                    double ss = sCt[d] - p1[d]; double s2 = sCt2[d] - p2[d];
                    r[j] += s2 - ss * ss / nn;
                }
            double res = ((r[0] + r[1]) + (r[2] + r[3])) + ((r[4] + r[5]) + (r[6] + r[7]));
            { double ss = sCt[32] - p1[32]; double s2 = sCt2[32] - p2[32]; res += s2 - ss * ss / nn; }
            val = sFc[cc] + res + PEN;
            mv = val; mi = tid;
        }
        // wave-level argmin (first-occurrence tie-break by slot index)
        #pragma unroll
        for (int off = 32; off >= 1; off >>= 1) {
            double ov = __shfl_down(mv, off);
            int oi = __shfl_down(mi, off);
            if (ov < mv || (ov == mv && oi < mi)) { mv = ov; mi = oi; }
        }
        if (lane == 0) { wMin[wv] = mv; wIdx[wv] = mi; }
        __syncthreads();
        if (tid == 0) {
            double bv = wMin[0]; int bi = wIdx[0];
            #pragma unroll
            for (int wj = 1; wj < 8; wj++) {
                double ov = wMin[wj]; int oi = wIdx[wj];
                if (ov < bv || (ov == bv && oi < bi)) { bv = ov; bi = oi; }
            }
            sFc[t] = bv;
            sPrev[t] = sCand[bi];
            sThr = bv + PEN;
        }
        __syncthreads();
        bool keep = (tid < ncand) && (val <= sThr);
        unsigned long long mask = __ballot(keep);
        if (lane == 0) grpCnt[wv] = __popcll(mask);
        __syncthreads();
        if (tid == 0) {
            int ex = 0;
            #pragma unroll
            for (int wj = 0; wj < 8; wj++) { grpOff[wj] = ex; ex += grpCnt[wj]; }
            sTotal = ex;
            sNcand = ex + 1;
        }
        __syncthreads();
        if (keep) {
            int pos = grpOff[wv] + __popcll(mask & ((1ull << lane) - 1ull));
            sNew[pos] = sCand[tid];
        }
        if (tid == 0) sNew[sTotal] = (unsigned short)t;
        __syncthreads();
        sCand[tid] = sNew[tid];
        __syncthreads();
    }
    prevG[b * 512 + tid] = (int)sPrev[tid];
}

// ---------------- backtrack + bounds + segment table + bin offsets (1 thread per batch)
__global__ void k_bounds(const int* __restrict__ prevG, int* __restrict__ bps, int* __restrict__ bnds,
                         int* __restrict__ segS, int* __restrict__ segE, int* __restrict__ nsegA,
                         int* __restrict__ binoff) {
    int b = threadIdx.x;
    if (b >= Bn) return;
    const int* pv = prevG + b * 512;
    int* bp = bps + b * 512;
    int* bd = bnds + b * 520;
    int cnt = 0, t = NF;
    while (t > 0) { bp[cnt++] = t; t = pv[t]; }
    // bp is descending; ascending-excluding-max = bp[cnt-1] .. bp[1]
    int nb = 1; bd[0] = 0;
    for (int i = cnt - 1; i >= 1; --i) {
        int k = bp[i];
        int bb = 32 * k;
        if (bb > Ln) bb = Ln;
        if (bb - bd[nb - 1] >= 8) bd[nb++] = bb;
    }
    if (Ln - bd[nb - 1] < 8 && nb > 1) nb--;
    bd[nb++] = Ln;
    int ns = nb - 1;
    nsegA[b] = ns;
    int off = 0;
    for (int j = 0; j < ns; j++) {
        int s = bd[j], e = bd[j + 1];
        segS[b * 512 + j] = s; segE[b * 512 + j] = e;
        binoff[b * 513 + j] = off;
        off += (e - s) >> 1;
    }
    binoff[b * 513 + ns] = off;
}

// ---------------- per-segment mean (double; bins k>=1 are insensitive to mean precision)
__global__ void k_segmean(const float* __restrict__ sig, const int* __restrict__ segS,
                          const int* __restrict__ segE, const int* __restrict__ nsegA,
                          double* __restrict__ segMean) {
    __shared__ double red[256];
    int b = blockIdx.y, j = blockIdx.x;
    if (j >= nsegA[b]) return;
    int s = segS[b * 512 + j], e = segE[b * 512 + j];
    double acc = 0.0;
    for (int i = s + threadIdx.x; i < e; i += 256) acc += (double)sig[b * Ln + i];
    red[threadIdx.x] = acc;
    __syncthreads();
    for (int st = 128; st >= 1; st >>= 1) {
        if (threadIdx.x < st) red[threadIdx.x] += red[threadIdx.x + st];
        __syncthreads();
    }
    if (threadIdx.x == 0) segMean[b * 512 + j] = red[0] / (double)(e - s);
}

// ---------------- segment DFT: one wave per (batch, bin-slot), rotation recurrence in double
__global__ __launch_bounds__(256) void k_spec(const float* __restrict__ sig,
                                              const double* __restrict__ segMean,
                                              const int* __restrict__ segS, const int* __restrict__ segE,
                                              const int* __restrict__ nsegA, const int* __restrict__ binoff,
                                              double* __restrict__ spec) {
    int b = blockIdx.y;
    int wv = threadIdx.x >> 6, lane = threadIdx.x & 63;
    int slot = blockIdx.x * 4 + wv;
    int ns = nsegA[b];
    const int* off = binoff + b * 513;
    if (slot >= off[ns]) return;
    int lo = 0, hi = ns - 1;
    while (lo < hi) { int mid = (lo + hi + 1) >> 1; if (off[mid] <= slot) lo = mid; else hi = mid - 1; }
    int j = lo;
    int s = segS[b * 512 + j], e = segE[b * 512 + j], n = e - s;
    int k = slot - off[j] + 1;
    float m32 = (float)segMean[b * 512 + j];
    long j0 = ((long)lane * (long)k) % (long)n;
    long js = (64L * (long)k) % (long)n;
    double a0 = (2.0 * M_PI * (double)j0) / (double)n;
    double as = (2.0 * M_PI * (double)js) / (double)n;
    double cr, sr, cb, sb;
    sincos(a0, &sr, &cr);
    sincos(as, &sb, &cb);
    double re = 0.0, im = 0.0;
    const float* sp = sig + b * Ln + s;
    for (int tt = lane; tt < n; tt += 64) {
        double v = (double)(sp[tt] - m32);
        re += v * cr;
        im += v * sr;
        double nc = cr * cb - sr * sb;
        sr = sr * cb + cr * sb;
        cr = nc;
    }
    #pragma unroll
    for (int o = 32; o >= 1; o >>= 1) { re += __shfl_down(re, o); im += __shfl_down(im, o); }
    if (lane == 0) spec[(size_t)b * TB + slot] = re * re + im * im;
}

// ---------------- per-segment stats: argmax bin, tot, centroid, bandwidth, patch length
__global__ void k_stats(const double* __restrict__ spec, const int* __restrict__ segS,
                        const int* __restrict__ segE, const int* __restrict__ nsegA,
                        const int* __restrict__ binoff, int* __restrict__ segPL,
                        double* __restrict__ segDP, double* __restrict__ segBW,
                        int* __restrict__ segNT) {
    __shared__ double rv[256]; __shared__ int ri[256];
    __shared__ double rt[256], rs[256];
    __shared__ double sC, sTot;
    int b = blockIdx.y, j = blockIdx.x;
    if (j >= nsegA[b]) return;
    int s = segS[b * 512 + j], e = segE[b * 512 + j], n = e - s, nf = n >> 1;
    const double* base = spec + (size_t)b * TB + binoff[b * 513 + j];
    int tid = threadIdx.x;
    double mv = -INFINITY; int mi = 0x7fffffff; double tot = 0.0, s1 = 0.0;
    for (int i = tid; i < nf; i += 256) {
        double vv = base[i];
        double f = (double)(i + 1) / (double)nf;
        tot += vv; s1 += vv * f;
        if (vv > mv) { mv = vv; mi = i; }
    }
    rv[tid] = mv; ri[tid] = mi; rt[tid] = tot; rs[tid] = s1;
    __syncthreads();
    for (int st = 128; st >= 1; st >>= 1) {
        if (tid < st) {
            double ov = rv[tid + st]; int oi = ri[tid + st];
            if (ov > rv[tid] || (ov == rv[tid] && oi < ri[tid])) { rv[tid] = ov; ri[tid] = oi; }
            rt[tid] += rt[tid + st]; rs[tid] += rs[tid + st];
        }
        __syncthreads();
    }
    if (tid == 0) { sTot = rt[0]; sC = rs[0] / rt[0]; }
    __syncthreads();
    double c = sC, totv = sTot;
    double s2 = 0.0;
    for (int i = tid; i < nf; i += 256) {
        double f = (double)(i + 1) / (double)nf;
        double d = f - c;
        s2 += base[i] * d * d;
    }
    rt[tid] = s2;
    __syncthreads();
    for (int st = 128; st >= 1; st >>= 1) {
        if (tid < st) rt[tid] += rt[tid + st];
        __syncthreads();
    }
    if (tid == 0) {
        double dp, bw;
        if (n < 4) { dp = (double)(n > 0 ? n : 1); bw = 0.0; }
        else if (!(totv > 0.0)) { dp = (double)n; bw = 0.0; }
        else { int kk = ri[0] + 1; dp = (double)n / (double)kk; bw = sqrt(rt[0] / totv); }
        double raw = 1.0 * dp / (1.0 + 1.0 * bw);
        double rr = rint(raw / 2.0);          // Python round(): half-to-even
        long pl = 2L * (long)rr;
        if (pl < 8) pl = 8;
        if (pl > 64) pl = 64;
        int nfull = n / (int)pl;
        int ntok = nfull + ((nfull * (int)pl < n) ? 1 : 0);
        segPL[b * 512 + j] = (int)pl; segDP[b * 512 + j] = dp;
        segBW[b * 512 + j] = bw; segNT[b * 512 + j] = ntok;
    }
}

// ---------------- token prefix offsets per batch
__global__ void k_tokpref(const int* __restrict__ nsegA, const int* __restrict__ segNT,
                          int* __restrict__ tokoff, int* __restrict__ ntokA) {
    int b = threadIdx.x;
    if (b >= Bn) return;
    int ns = nsegA[b]; int off = 0;
    for (int j = 0; j < ns; j++) { tokoff[b * 513 + j] = off; off += segNT[b * 512 + j]; }
    tokoff[b * 513 + ns] = off;
    ntokA[b] = off;
}

// ---------------- fill all outputs: one block per (batch, token)
__global__ __launch_bounds__(256) void k_fill(const float* __restrict__ x,
                                              const int* __restrict__ segS, const int* __restrict__ segE,
                                              const int* __restrict__ segPL, const double* __restrict__ segDP,
                                              const double* __restrict__ segBW, const int* __restrict__ nsegA,
                                              const int* __restrict__ tokoff, const int* __restrict__ ntokA,
                                              float* __restrict__ out, int MT) {
    int b = blockIdx.y, tok = blockIdx.x;
    int nt = ntokA[b];
    if (tok >= nt) return;
    int ns = nsegA[b];
    const int* toff = tokoff + b * 513;
    int lo = 0, hi = ns - 1;
    while (lo < hi) { int mid = (lo + hi + 1) >> 1; if (toff[mid] <= tok) lo = mid; else hi = mid - 1; }
    int j = lo;
    int s = segS[b * 512 + j], e = segE[b * 512 + j], pl = segPL[b * 512 + j];
    int idx = tok - toff[j];
    int nfull = (e - s) / pl;
    int st, en;
    if (idx < nfull) { st = s + idx * pl; en = st + pl; }
    else { st = s + nfull * pl; en = e; }
    int ilen = en - st;
    float scale = (float)ilen / 16.0f;
    int tid = threadIdx.x;
    size_t pbase = ((size_t)(b * MT + tok)) * (Cn * 16);
    const float* xb = x + (size_t)b * Cn * Ln;
    #pragma unroll
    for (int r = 0; r < 2; r++) {
        int eidx = tid + r * 256;
        int c = eidx >> 4, jo = eidx & 15;
        float coords = ((float)jo + 0.5f) * scale - 0.5f;
        if (coords < 0.0f) coords = 0.0f;
        float mx = (float)(ilen - 1);
        if (coords > mx) coords = mx;
        int l2 = (int)floorf(coords);
        int h2 = l2 + 1;
        if (h2 > ilen - 1) h2 = ilen - 1;
        float w = coords - (float)l2;
        const float* xc = xb + (size_t)c * Ln + st;
        out[pbase + eidx] = xc[l2] * (1.0f - w) + xc[h2] * w;
    }
    if (tid == 0) {
        size_t BT = (size_t)Bn * MT;
        size_t o_mask = BT * 512;
        size_t pos = (size_t)b * MT + tok;
        out[o_mask + pos] = 1.0f;                                  // mask
        out[o_mask + BT + pos] = (float)st;                        // start
        out[o_mask + 2 * BT + pos] = (float)en;                    // end
        out[o_mask + 3 * BT + pos] = (((float)st + (float)en) - 1.0f) * 0.5f / 16383.0f;  // center
        out[o_mask + 4 * BT + pos] = (float)(en - st) / 16384.0f;  // span
        double dp = segDP[b * 512 + j], bwv = segBW[b * 512 + j];
        size_t o_rg = o_mask + 5 * BT;
        out[o_rg + pos * 3 + 0] = (float)(dp / 16384.0);
        out[o_rg + pos * 3 + 1] = (float)bwv;
        out[o_rg + pos * 3 + 2] = (float)((double)(e - s) / 16384.0);
        if (tok == 0) out[o_mask + 8 * BT + b] = (float)nt;        // n_tok
    }
}

extern "C" void kernel_launch(void* const* d_in, const int* in_sizes, int n_in,
                              void* d_out, int out_size, void* d_ws, size_t ws_size,
                              hipStream_t stream) {
    (void)in_sizes; (void)n_in; (void)ws_size;
    const float* x = (const float*)d_in[0];
    float* out = (float*)d_out;
    char* ws = (char*)d_ws;
    size_t o = 0;
    auto alloc = [&](size_t bytes) -> char* {
        char* r = ws + o;
        o = (o + bytes + 511) & ~(size_t)511;
        return r;
    };
    float* sig = (float*)alloc((size_t)Bn * Ln * 4);
    float* fm = (float*)alloc((size_t)Bn * NF * 4);
    double* feats = (double*)alloc((size_t)Bn * NF * NB * 8);
    double* cs = (double*)alloc((size_t)Bn * 512 * NB * 8);
    double* cs2 = (double*)alloc((size_t)Bn * 512 * NB * 8);
    int* prevG = (int*)alloc((size_t)Bn * 512 * 4);
    int* bps = (int*)alloc((size_t)Bn * 512 * 4);
    int* bnds = (int*)alloc((size_t)Bn * 520 * 4);
    int* nsegA = (int*)alloc((size_t)Bn * 4);
    int* segS = (int*)alloc((size_t)Bn * 512 * 4);
    int* segE = (int*)alloc((size_t)Bn * 512 * 4);
    int* segPL = (int*)alloc((size_t)Bn * 512 * 4);
    int* segNT = (int*)alloc((size_t)Bn * 512 * 4);
    double* segDP = (double*)alloc((size_t)Bn * 512 * 8);
    double* segBW = (double*)alloc((size_t)Bn * 512 * 8);
    double* segMean = (double*)alloc((size_t)Bn * 512 * 8);
    int* binoff = (int*)alloc((size_t)Bn * 513 * 4);
    int* tokoff = (int*)alloc((size_t)Bn * 513 * 4);
    int* ntokA = (int*)alloc((size_t)Bn * 4);
    double* spec = (double*)alloc((size_t)Bn * TB * 8);

    int MT = (out_size / Bn - 1) / 520;   // out_size = Bn*(MT*520 + 1)

    hipMemsetAsync(d_out, 0, (size_t)out_size * 4, stream);
    k_sig<<<(Bn * Ln + 255) / 256, 256, 0, stream>>>(x, sig);
    k_fmean<<<(Bn * NF + 255) / 256, 256, 0, stream>>>(sig, fm);
    k_feats<<<Bn * NF, 64, 0, stream>>>(sig, fm, feats);
    k_cumsum<<<(Bn * NB + 255) / 256, 256, 0, stream>>>(feats, cs, cs2);
    k_pelt<<<Bn, 512, 0, stream>>>(cs, cs2, prevG);
    k_bounds<<<1, 32, 0, stream>>>(prevG, bps, bnds, segS, segE, nsegA, binoff);
    k_segmean<<<dim3(MAXSEG, Bn), 256, 0, stream>>>(sig, segS, segE, nsegA, segMean);
    k_spec<<<dim3(TB / 4, Bn), 256, 0, stream>>>(sig, segMean, segS, segE, nsegA, binoff, spec);
    k_stats<<<dim3(MAXSEG, Bn), 256, 0, stream>>>(spec, segS, segE, nsegA, binoff,
                                                  segPL, segDP, segBW, segNT);
    k_tokpref<<<1, 32, 0, stream>>>(nsegA, segNT, tokoff, ntokA);
    if (MT > 0)
        k_fill<<<dim3(MT, Bn), 256, 0, stream>>>(x, segS, segE, segPL, segDP, segBW,
                                                 nsegA, tokoff, ntokA, out, MT);
}

// Round 2
// 2700.849 us; speedup vs baseline: 1.0466x; 1.0466x over previous
//
#include <hip/hip_runtime.h>
#include <math.h>

#define Bn 32
#define Cn 32
#define Ln 16384
#define NF 511      // number of spectrogram frames
#define NB 33       // rfft bins of 64-pt window
#define MAXSEG 512
#define TB 8192     // total spectral bins per batch (sum of nf over segments = L/2)
#define PEN 5.0

// ---------------- sig = x.mean(axis=channels), float32 sequential (numpy axis-0 reduce order)
__global__ void k_sig(const float* __restrict__ x, float* __restrict__ sig) {
    int idx = blockIdx.x * 256 + threadIdx.x;
    if (idx >= Bn * Ln) return;
    int b = idx >> 14;
    int t = idx & (Ln - 1);
    const float* p = x + ((size_t)b * Cn) * Ln + t;
    float a = p[0];
    #pragma unroll
    for (int c = 1; c < Cn; c++) a += p[(size_t)c * Ln];
    sig[idx] = a / 32.0f;
}

// ---------------- frame means: numpy scalar pairwise 8-accumulator pattern, n=64, float32
__global__ void k_fmean(const float* __restrict__ sig, float* __restrict__ fm) {
    int idx = blockIdx.x * 256 + threadIdx.x;
    if (idx >= Bn * NF) return;
    int b = idx / NF, f = idx - b * NF;
    const float* a = sig + b * Ln + f * 32;
    float r[8];
    #pragma unroll
    for (int j = 0; j < 8; j++) r[j] = a[j];
    #pragma unroll
    for (int base = 8; base < 64; base += 8)
        #pragma unroll
        for (int j = 0; j < 8; j++) r[j] += a[base + j];
    float res = ((r[0] + r[1]) + (r[2] + r[3])) + ((r[4] + r[5]) + (r[6] + r[7]));
    fm[idx] = res / 64.0f;
}

// ---------------- feats = log(|rfft(hann * (frame - mean))|^2 + 1e-8), double
__global__ void k_feats(const float* __restrict__ sig, const float* __restrict__ fm,
                        double* __restrict__ feats) {
    __shared__ double v[64], ct[64], stb[64];
    int bf = blockIdx.x;
    int b = bf / NF, f = bf - b * NF;
    int i = threadIdx.x;  // 0..63
    double ang = (2.0 * M_PI * (double)i) / 64.0;
    double sn, cx;
    sincos(ang, &sn, &cx);
    ct[i] = cx; stb[i] = sn;
    int n2 = 2 * i - 63;                       // np.hanning: arange(1-M, M, 2)
    double w = 0.5 + 0.5 * cos((M_PI * (double)n2) / 63.0);
    float m = fm[bf];
    v[i] = (double)(sig[b * Ln + f * 32 + i] - m) * w;   // f32 subtract, f64 window mult
    __syncthreads();
    if (i < NB) {
        double re = 0.0, im = 0.0;
        for (int t = 0; t < 64; t++) {
            int j = (t * i) & 63;
            re += v[t] * ct[j];
            im += v[t] * stb[j];
        }
        double spec = re * re + im * im;
        feats[(size_t)bf * NB + i] = log(spec + 1e-8);
    }
}

// ---------------- cs / cs2 cumsums (sequential double, numpy cumsum order)
__global__ void k_cumsum(const double* __restrict__ feats, double* __restrict__ cs,
                         double* __restrict__ cs2) {
    int idx = blockIdx.x * 256 + threadIdx.x;
    if (idx >= Bn * NB) return;
    int b = idx / NB, d = idx - b * NB;
    const double* fp = feats + (size_t)b * NF * NB + d;
    double* c1 = cs + (size_t)b * 512 * NB + d;
    double* c2 = cs2 + (size_t)b * 512 * NB + d;
    double a1 = 0.0, a2 = 0.0;
    c1[0] = 0.0; c2[0] = 0.0;
    for (int t = 0; t < NF; t++) {
        double vv = fp[(size_t)t * NB];
        a1 += vv;
        a2 += vv * vv;
        c1[(size_t)(t + 1) * NB] = a1;
        c2[(size_t)(t + 1) * NB] = a2;
    }
}

// ---------------- PELT DP, ONE WAVE per batch, wave-synchronous (no multi-wave barriers)
__global__ __launch_bounds__(64) void k_pelt(const double* __restrict__ cs,
                                             const double* __restrict__ cs2,
                                             int* __restrict__ prevG) {
    __shared__ double sFc[512];
    __shared__ double sVal[512];
    __shared__ unsigned short sCand[512];

    int b = blockIdx.x;
    int lane = threadIdx.x;
    const double* c1 = cs + (size_t)b * 512 * NB;
    const double* c2 = cs2 + (size_t)b * 512 * NB;

    if (lane == 0) { sFc[0] = -PEN; sCand[0] = 0; }
    __syncthreads();

    int ncand = 1;
    for (int t = 1; t <= NF; t++) {
        const double* ct1 = c1 + (size_t)t * NB;
        const double* ct2 = c2 + (size_t)t * NB;
        int passes = (ncand + 63) >> 6;
        double bmv = INFINITY;
        int bmi = 0x7fffffff;
        for (int p = 0; p < passes; p++) {
            int slot = (p << 6) + lane;
            double val = INFINITY;
            if (slot < ncand) {
                int cc = sCand[slot];
                double nn = (double)(t - cc);
                const double* p1 = c1 + (size_t)cc * NB;
                const double* p2 = c2 + (size_t)cc * NB;
                // numpy pairwise sum over 33 dims: 8 accumulators + remainder
                double r[8];
                #pragma unroll
                for (int j = 0; j < 8; j++) {
                    double ss = ct1[j] - p1[j]; double s2 = ct2[j] - p2[j];
                    r[j] = s2 - ss * ss / nn;
                }
                #pragma unroll
                for (int base = 8; base < 32; base += 8)
                    #pragma unroll
                    for (int j = 0; j < 8; j++) {
                        int d = base + j;
                        double ss = ct1[d] - p1[d]; double s2 = ct2[d] - p2[d];
                        r[j] += s2 - ss * ss / nn;
                    }
                double res = ((r[0] + r[1]) + (r[2] + r[3])) + ((r[4] + r[5]) + (r[6] + r[7]));
                { double ss = ct1[32] - p1[32]; double s2 = ct2[32] - p2[32]; res += s2 - ss * ss / nn; }
                val = sFc[cc] + res + PEN;
                if (val < bmv) { bmv = val; bmi = slot; }  // strict <: earlier slot wins ties
            }
            sVal[slot] = val;
        }
        // butterfly argmin across 64 lanes, lexicographic (val, slot) -> all lanes converge
        #pragma unroll
        for (int off = 1; off < 64; off <<= 1) {
            double ov = __shfl_xor(bmv, off);
            int oi = __shfl_xor(bmi, off);
            if (ov < bmv || (ov == bmv && oi < bmi)) { bmv = ov; bmi = oi; }
        }
        double thr = bmv + PEN;
        if (lane == 0) {
            sFc[t] = bmv;
            prevG[b * 512 + t] = (int)sCand[bmi];
        }
        __syncthreads();  // single wave: compiles to waitcnt only, cheap
        // in-place prune/compact, order-preserving (writes land at pos <= slot)
        int base = 0;
        for (int p = 0; p < passes; p++) {
            int slot = (p << 6) + lane;
            int cc = (slot < ncand) ? (int)sCand[slot] : 0;
            bool keep = (slot < ncand) && (sVal[slot] <= thr);
            unsigned long long mask = __ballot(keep);
            if (keep) sCand[base + __popcll(mask & ((1ull << lane) - 1ull))] = (unsigned short)cc;
            base += (int)__popcll(mask);
        }
        if (lane == 0) sCand[base] = (unsigned short)t;
        ncand = base + 1;
        __syncthreads();
    }
}

// ---------------- backtrack + bounds + segment table + bin offsets (1 thread per batch)
__global__ void k_bounds(const int* __restrict__ prevG, int* __restrict__ bps, int* __restrict__ bnds,
                         int* __restrict__ segS, int* __restrict__ segE, int* __restrict__ nsegA,
                         int* __restrict__ binoff) {
    int b = threadIdx.x;
    if (b >= Bn) return;
    const int* pv = prevG + b * 512;
    int* bp = bps + b * 512;
    int* bd = bnds + b * 520;
    int cnt = 0, t = NF;
    while (t > 0) { bp[cnt++] = t; t = pv[t]; }
    // bp is descending; ascending-excluding-max = bp[cnt-1] .. bp[1]
    int nb = 1; bd[0] = 0;
    for (int i = cnt - 1; i >= 1; --i) {
        int k = bp[i];
        int bb = 32 * k;
        if (bb > Ln) bb = Ln;
        if (bb - bd[nb - 1] >= 8) bd[nb++] = bb;
    }
    if (Ln - bd[nb - 1] < 8 && nb > 1) nb--;
    bd[nb++] = Ln;
    int ns = nb - 1;
    nsegA[b] = ns;
    int off = 0;
    for (int j = 0; j < ns; j++) {
        int s = bd[j], e = bd[j + 1];
        segS[b * 512 + j] = s; segE[b * 512 + j] = e;
        binoff[b * 513 + j] = off;
        off += (e - s) >> 1;
    }
    binoff[b * 513 + ns] = off;
}

// ---------------- per-segment mean (double; bins k>=1 are insensitive to mean precision)
__global__ void k_segmean(const float* __restrict__ sig, const int* __restrict__ segS,
                          const int* __restrict__ segE, const int* __restrict__ nsegA,
                          double* __restrict__ segMean) {
    __shared__ double red[256];
    int b = blockIdx.y, j = blockIdx.x;
    if (j >= nsegA[b]) return;
    int s = segS[b * 512 + j], e = segE[b * 512 + j];
    double acc = 0.0;
    for (int i = s + threadIdx.x; i < e; i += 256) acc += (double)sig[b * Ln + i];
    red[threadIdx.x] = acc;
    __syncthreads();
    for (int st = 128; st >= 1; st >>= 1) {
        if (threadIdx.x < st) red[threadIdx.x] += red[threadIdx.x + st];
        __syncthreads();
    }
    if (threadIdx.x == 0) segMean[b * 512 + j] = red[0] / (double)(e - s);
}

// ---------------- segment DFT: one wave per (batch, bin-slot), rotation recurrence in double
__global__ __launch_bounds__(256) void k_spec(const float* __restrict__ sig,
                                              const double* __restrict__ segMean,
                                              const int* __restrict__ segS, const int* __restrict__ segE,
                                              const int* __restrict__ nsegA, const int* __restrict__ binoff,
                                              double* __restrict__ spec) {
    int b = blockIdx.y;
    int wv = threadIdx.x >> 6, lane = threadIdx.x & 63;
    int slot = blockIdx.x * 4 + wv;
    int ns = nsegA[b];
    const int* off = binoff + b * 513;
    if (slot >= off[ns]) return;
    int lo = 0, hi = ns - 1;
    while (lo < hi) { int mid = (lo + hi + 1) >> 1; if (off[mid] <= slot) lo = mid; else hi = mid - 1; }
    int j = lo;
    int s = segS[b * 512 + j], e = segE[b * 512 + j], n = e - s;
    int k = slot - off[j] + 1;
    float m32 = (float)segMean[b * 512 + j];
    long j0 = ((long)lane * (long)k) % (long)n;
    long js = (64L * (long)k) % (long)n;
    double a0 = (2.0 * M_PI * (double)j0) / (double)n;
    double as = (2.0 * M_PI * (double)js) / (double)n;
    double cr, sr, cb, sb;
    sincos(a0, &sr, &cr);
    sincos(as, &sb, &cb);
    double re = 0.0, im = 0.0;
    const float* sp = sig + b * Ln + s;
    for (int tt = lane; tt < n; tt += 64) {
        double v = (double)(sp[tt] - m32);
        re += v * cr;
        im += v * sr;
        double nc = cr * cb - sr * sb;
        sr = sr * cb + cr * sb;
        cr = nc;
    }
    #pragma unroll
    for (int o = 32; o >= 1; o >>= 1) { re += __shfl_down(re, o); im += __shfl_down(im, o); }
    if (lane == 0) spec[(size_t)b * TB + slot] = re * re + im * im;
}

// ---------------- per-segment stats: argmax bin, tot, centroid, bandwidth, patch length
__global__ void k_stats(const double* __restrict__ spec, const int* __restrict__ segS,
                        const int* __restrict__ segE, const int* __restrict__ nsegA,
                        const int* __restrict__ binoff, int* __restrict__ segPL,
                        double* __restrict__ segDP, double* __restrict__ segBW,
                        int* __restrict__ segNT) {
    __shared__ double rv[256]; __shared__ int ri[256];
    __shared__ double rt[256], rs[256];
    __shared__ double sC, sTot;
    int b = blockIdx.y, j = blockIdx.x;
    if (j >= nsegA[b]) return;
    int s = segS[b * 512 + j], e = segE[b * 512 + j], n = e - s, nf = n >> 1;
    const double* base = spec + (size_t)b * TB + binoff[b * 513 + j];
    int tid = threadIdx.x;
    double mv = -INFINITY; int mi = 0x7fffffff; double tot = 0.0, s1 = 0.0;
    for (int i = tid; i < nf; i += 256) {
        double vv = base[i];
        double f = (double)(i + 1) / (double)nf;
        tot += vv; s1 += vv * f;
        if (vv > mv) { mv = vv; mi = i; }
    }
    rv[tid] = mv; ri[tid] = mi; rt[tid] = tot; rs[tid] = s1;
    __syncthreads();
    for (int st = 128; st >= 1; st >>= 1) {
        if (tid < st) {
            double ov = rv[tid + st]; int oi = ri[tid + st];
            if (ov > rv[tid] || (ov == rv[tid] && oi < ri[tid])) { rv[tid] = ov; ri[tid] = oi; }
            rt[tid] += rt[tid + st]; rs[tid] += rs[tid + st];
        }
        __syncthreads();
    }
    if (tid == 0) { sTot = rt[0]; sC = rs[0] / rt[0]; }
    __syncthreads();
    double c = sC, totv = sTot;
    double s2 = 0.0;
    for (int i = tid; i < nf; i += 256) {
        double f = (double)(i + 1) / (double)nf;
        double d = f - c;
        s2 += base[i] * d * d;
    }
    rt[tid] = s2;
    __syncthreads();
    for (int st = 128; st >= 1; st >>= 1) {
        if (tid < st) rt[tid] += rt[tid + st];
        __syncthreads();
    }
    if (tid == 0) {
        double dp, bw;
        if (n < 4) { dp = (double)(n > 0 ? n : 1); bw = 0.0; }
        else if (!(totv > 0.0)) { dp = (double)n; bw = 0.0; }
        else { int kk = ri[0] + 1; dp = (double)n / (double)kk; bw = sqrt(rt[0] / totv); }
        double raw = 1.0 * dp / (1.0 + 1.0 * bw);
        double rr = rint(raw / 2.0);          // Python round(): half-to-even
        long pl = 2L * (long)rr;
        if (pl < 8) pl = 8;
        if (pl > 64) pl = 64;
        int nfull = n / (int)pl;
        int ntok = nfull + ((nfull * (int)pl < n) ? 1 : 0);
        segPL[b * 512 + j] = (int)pl; segDP[b * 512 + j] = dp;
        segBW[b * 512 + j] = bw; segNT[b * 512 + j] = ntok;
    }
}

// ---------------- token prefix offsets per batch
__global__ void k_tokpref(const int* __restrict__ nsegA, const int* __restrict__ segNT,
                          int* __restrict__ tokoff, int* __restrict__ ntokA) {
    int b = threadIdx.x;
    if (b >= Bn) return;
    int ns = nsegA[b]; int off = 0;
    for (int j = 0; j < ns; j++) { tokoff[b * 513 + j] = off; off += segNT[b * 512 + j]; }
    tokoff[b * 513 + ns] = off;
    ntokA[b] = off;
}

// ---------------- fill all outputs: one block per (batch, token)
__global__ __launch_bounds__(256) void k_fill(const float* __restrict__ x,
                                              const int* __restrict__ segS, const int* __restrict__ segE,
                                              const int* __restrict__ segPL, const double* __restrict__ segDP,
                                              const double* __restrict__ segBW, const int* __restrict__ nsegA,
                                              const int* __restrict__ tokoff, const int* __restrict__ ntokA,
                                              float* __restrict__ out, int MT) {
    int b = blockIdx.y, tok = blockIdx.x;
    int nt = ntokA[b];
    if (tok >= nt) return;
    int ns = nsegA[b];
    const int* toff = tokoff + b * 513;
    int lo = 0, hi = ns - 1;
    while (lo < hi) { int mid = (lo + hi + 1) >> 1; if (toff[mid] <= tok) lo = mid; else hi = mid - 1; }
    int j = lo;
    int s = segS[b * 512 + j], e = segE[b * 512 + j], pl = segPL[b * 512 + j];
    int idx = tok - toff[j];
    int nfull = (e - s) / pl;
    int st, en;
    if (idx < nfull) { st = s + idx * pl; en = st + pl; }
    else { st = s + nfull * pl; en = e; }
    int ilen = en - st;
    float scale = (float)ilen / 16.0f;
    int tid = threadIdx.x;
    size_t pbase = ((size_t)(b * MT + tok)) * (Cn * 16);
    const float* xb = x + (size_t)b * Cn * Ln;
    #pragma unroll
    for (int r = 0; r < 2; r++) {
        int eidx = tid + r * 256;
        int c = eidx >> 4, jo = eidx & 15;
        float coords = ((float)jo + 0.5f) * scale - 0.5f;
        if (coords < 0.0f) coords = 0.0f;
        float mx = (float)(ilen - 1);
        if (coords > mx) coords = mx;
        int l2 = (int)floorf(coords);
        int h2 = l2 + 1;
        if (h2 > ilen - 1) h2 = ilen - 1;
        float w = coords - (float)l2;
        const float* xc = xb + (size_t)c * Ln + st;
        out[pbase + eidx] = xc[l2] * (1.0f - w) + xc[h2] * w;
    }
    if (tid == 0) {
        size_t BT = (size_t)Bn * MT;
        size_t o_mask = BT * 512;
        size_t pos = (size_t)b * MT + tok;
        out[o_mask + pos] = 1.0f;                                  // mask
        out[o_mask + BT + pos] = (float)st;                        // start
        out[o_mask + 2 * BT + pos] = (float)en;                    // end
        out[o_mask + 3 * BT + pos] = (((float)st + (float)en) - 1.0f) * 0.5f / 16383.0f;  // center
        out[o_mask + 4 * BT + pos] = (float)(en - st) / 16384.0f;  // span
        double dp = segDP[b * 512 + j], bwv = segBW[b * 512 + j];
        size_t o_rg = o_mask + 5 * BT;
        out[o_rg + pos * 3 + 0] = (float)(dp / 16384.0);
        out[o_rg + pos * 3 + 1] = (float)bwv;
        out[o_rg + pos * 3 + 2] = (float)((double)(e - s) / 16384.0);
        if (tok == 0) out[o_mask + 8 * BT + b] = (float)nt;        // n_tok
    }
}

extern "C" void kernel_launch(void* const* d_in, const int* in_sizes, int n_in,
                              void* d_out, int out_size, void* d_ws, size_t ws_size,
                              hipStream_t stream) {
    (void)in_sizes; (void)n_in; (void)ws_size;
    const float* x = (const float*)d_in[0];
    float* out = (float*)d_out;
    char* ws = (char*)d_ws;
    size_t o = 0;
    auto alloc = [&](size_t bytes) -> char* {
        char* r = ws + o;
        o = (o + bytes + 511) & ~(size_t)511;
        return r;
    };
    float* sig = (float*)alloc((size_t)Bn * Ln * 4);
    float* fm = (float*)alloc((size_t)Bn * NF * 4);
    double* feats = (double*)alloc((size_t)Bn * NF * NB * 8);
    double* cs = (double*)alloc((size_t)Bn * 512 * NB * 8);
    double* cs2 = (double*)alloc((size_t)Bn * 512 * NB * 8);
    int* prevG = (int*)alloc((size_t)Bn * 512 * 4);
    int* bps = (int*)alloc((size_t)Bn * 512 * 4);
    int* bnds = (int*)alloc((size_t)Bn * 520 * 4);
    int* nsegA = (int*)alloc((size_t)Bn * 4);
    int* segS = (int*)alloc((size_t)Bn * 512 * 4);
    int* segE = (int*)alloc((size_t)Bn * 512 * 4);
    int* segPL = (int*)alloc((size_t)Bn * 512 * 4);
    int* segNT = (int*)alloc((size_t)Bn * 512 * 4);
    double* segDP = (double*)alloc((size_t)Bn * 512 * 8);
    double* segBW = (double*)alloc((size_t)Bn * 512 * 8);
    double* segMean = (double*)alloc((size_t)Bn * 512 * 8);
    int* binoff = (int*)alloc((size_t)Bn * 513 * 4);
    int* tokoff = (int*)alloc((size_t)Bn * 513 * 4);
    int* ntokA = (int*)alloc((size_t)Bn * 4);
    double* spec = (double*)alloc((size_t)Bn * TB * 8);

    int MT = (out_size / Bn - 1) / 520;   // out_size = Bn*(MT*520 + 1)

    hipMemsetAsync(d_out, 0, (size_t)out_size * 4, stream);
    k_sig<<<(Bn * Ln + 255) / 256, 256, 0, stream>>>(x, sig);
    k_fmean<<<(Bn * NF + 255) / 256, 256, 0, stream>>>(sig, fm);
    k_feats<<<Bn * NF, 64, 0, stream>>>(sig, fm, feats);
    k_cumsum<<<(Bn * NB + 255) / 256, 256, 0, stream>>>(feats, cs, cs2);
    k_pelt<<<Bn, 64, 0, stream>>>(cs, cs2, prevG);
    k_bounds<<<1, 32, 0, stream>>>(prevG, bps, bnds, segS, segE, nsegA, binoff);
    k_segmean<<<dim3(MAXSEG, Bn), 256, 0, stream>>>(sig, segS, segE, nsegA, segMean);
    k_spec<<<dim3(TB / 4, Bn), 256, 0, stream>>>(sig, segMean, segS, segE, nsegA, binoff, spec);
    k_stats<<<dim3(MAXSEG, Bn), 256, 0, stream>>>(spec, segS, segE, nsegA, binoff,
                                                  segPL, segDP, segBW, segNT);
    k_tokpref<<<1, 32, 0, stream>>>(nsegA, segNT, tokoff, ntokA);
    if (MT > 0)
        k_fill<<<dim3(MT, Bn), 256, 0, stream>>>(x, segS, segE, segPL, segDP, segBW,
                                                 nsegA, tokoff, ntokA, out, MT);
}

// Round 3
// 1648.256 us; speedup vs baseline: 1.7150x; 1.6386x over previous
//
#include <hip/hip_runtime.h>
#include <math.h>

#define Bn 32
#define Cn 32
#define Ln 16384
#define NF 511      // number of spectrogram frames
#define NB 33       // rfft bins of 64-pt window
#define MAXSEG 512
#define TB 8192     // total spectral bins per batch (sum of nf over segments = L/2)
#define PEN 5.0

// ---------------- sig = x.mean(axis=channels), float32 sequential (numpy axis-0 reduce order)
__global__ void k_sig(const float* __restrict__ x, float* __restrict__ sig) {
    int idx = blockIdx.x * 256 + threadIdx.x;
    if (idx >= Bn * Ln) return;
    int b = idx >> 14;
    int t = idx & (Ln - 1);
    const float* p = x + ((size_t)b * Cn) * Ln + t;
    float a = p[0];
    #pragma unroll
    for (int c = 1; c < Cn; c++) a += p[(size_t)c * Ln];
    sig[idx] = a / 32.0f;
}

// ---------------- frame means: numpy scalar pairwise 8-accumulator pattern, n=64, float32
__global__ void k_fmean(const float* __restrict__ sig, float* __restrict__ fm) {
    int idx = blockIdx.x * 256 + threadIdx.x;
    if (idx >= Bn * NF) return;
    int b = idx / NF, f = idx - b * NF;
    const float* a = sig + b * Ln + f * 32;
    float r[8];
    #pragma unroll
    for (int j = 0; j < 8; j++) r[j] = a[j];
    #pragma unroll
    for (int base = 8; base < 64; base += 8)
        #pragma unroll
        for (int j = 0; j < 8; j++) r[j] += a[base + j];
    float res = ((r[0] + r[1]) + (r[2] + r[3])) + ((r[4] + r[5]) + (r[6] + r[7]));
    fm[idx] = res / 64.0f;
}

// ---------------- feats = log(|rfft(hann * (frame - mean))|^2 + 1e-8), double
__global__ void k_feats(const float* __restrict__ sig, const float* __restrict__ fm,
                        double* __restrict__ feats) {
    __shared__ double v[64], ct[64], stb[64];
    int bf = blockIdx.x;
    int b = bf / NF, f = bf - b * NF;
    int i = threadIdx.x;  // 0..63
    double ang = (2.0 * M_PI * (double)i) / 64.0;
    double sn, cx;
    sincos(ang, &sn, &cx);
    ct[i] = cx; stb[i] = sn;
    int n2 = 2 * i - 63;                       // np.hanning: arange(1-M, M, 2)
    double w = 0.5 + 0.5 * cos((M_PI * (double)n2) / 63.0);
    float m = fm[bf];
    v[i] = (double)(sig[b * Ln + f * 32 + i] - m) * w;   // f32 subtract, f64 window mult
    __syncthreads();
    if (i < NB) {
        double re = 0.0, im = 0.0;
        for (int t = 0; t < 64; t++) {
            int j = (t * i) & 63;
            re += v[t] * ct[j];
            im += v[t] * stb[j];
        }
        double spec = re * re + im * im;
        feats[(size_t)bf * NB + i] = log(spec + 1e-8);
    }
}

// ---------------- cs / cs2 cumsums (sequential double, numpy cumsum order)
__global__ void k_cumsum(const double* __restrict__ feats, double* __restrict__ cs,
                         double* __restrict__ cs2) {
    int idx = blockIdx.x * 256 + threadIdx.x;
    if (idx >= Bn * NB) return;
    int b = idx / NB, d = idx - b * NB;
    const double* fp = feats + (size_t)b * NF * NB + d;
    double* c1 = cs + (size_t)b * 512 * NB + d;
    double* c2 = cs2 + (size_t)b * 512 * NB + d;
    double a1 = 0.0, a2 = 0.0;
    c1[0] = 0.0; c2[0] = 0.0;
    for (int t = 0; t < NF; t++) {
        double vv = fp[(size_t)t * NB];
        a1 += vv;
        a2 += vv * vv;
        c1[(size_t)(t + 1) * NB] = a1;
        c2[(size_t)(t + 1) * NB] = a2;
    }
}

// ---------------- precompute cost(c,t) for all pairs, massively parallel, exact numpy op order
__global__ __launch_bounds__(256) void k_cost(const double* __restrict__ cs,
                                              const double* __restrict__ cs2,
                                              double* __restrict__ costM) {
    int t = blockIdx.x + 1;   // 1..NF
    int b = blockIdx.y;
    const double* c1 = cs + (size_t)b * 512 * NB;
    const double* c2 = cs2 + (size_t)b * 512 * NB;
    __shared__ double sct1[NB], sct2[NB];
    if (threadIdx.x < NB) {
        sct1[threadIdx.x] = c1[(size_t)t * NB + threadIdx.x];
        sct2[threadIdx.x] = c2[(size_t)t * NB + threadIdx.x];
    }
    __syncthreads();
    double* outp = costM + ((size_t)b * 512 + (size_t)t) * 512;
    for (int c = threadIdx.x; c < t; c += 256) {
        double nn = (double)(t - c);
        const double* p1 = c1 + (size_t)c * NB;
        const double* p2 = c2 + (size_t)c * NB;
        // numpy pairwise sum over 33 dims: 8 accumulators + remainder
        double r[8];
        #pragma unroll
        for (int j = 0; j < 8; j++) {
            double ss = sct1[j] - p1[j]; double s2 = sct2[j] - p2[j];
            r[j] = s2 - ss * ss / nn;
        }
        #pragma unroll
        for (int base = 8; base < 32; base += 8)
            #pragma unroll
            for (int j = 0; j < 8; j++) {
                int d = base + j;
                double ss = sct1[d] - p1[d]; double s2 = sct2[d] - p2[d];
                r[j] += s2 - ss * ss / nn;
            }
        double res = ((r[0] + r[1]) + (r[2] + r[3])) + ((r[4] + r[5]) + (r[6] + r[7]));
        { double ss = sct1[32] - p1[32]; double s2 = sct2[32] - p2[32]; res += s2 - ss * ss / nn; }
        outp[c] = res;
    }
}

// ---------------- PELT DP with precomputed costs: one wave/batch, bitmask candidates,
// Fc in registers, contiguous row reads prefetched one iteration ahead. No LDS, no barriers.
__global__ __launch_bounds__(64) void k_pelt(const double* __restrict__ costM,
                                             int* __restrict__ prevG) {
    int b = blockIdx.x;
    int lane = threadIdx.x;
    const double* cm = costM + (size_t)b * 512 * 512;

    unsigned long long cmask[8] = {1ull, 0, 0, 0, 0, 0, 0, 0};
    double fcreg[8];   // Fc[p*64 + lane], owned by this lane
    #pragma unroll
    for (int p = 0; p < 8; p++) fcreg[p] = INFINITY;
    if (lane == 0) fcreg[0] = -PEN;   // Fc[0]

    double cur[8];
    #pragma unroll
    for (int p = 0; p < 8; p++) cur[p] = cm[512 + (p << 6) + lane];   // row t=1

    for (int t = 1; t <= NF; t++) {
        double nxt[8];
        if (t < NF) {
            #pragma unroll
            for (int p = 0; p < 8; p++) nxt[p] = cm[(size_t)(t + 1) * 512 + (p << 6) + lane];
        }
        double vals[8];
        double bv = INFINITY; int bc = 0x7fffffff;
        #pragma unroll
        for (int p = 0; p < 8; p++) {
            int c = (p << 6) + lane;
            bool isc = ((cmask[p] >> lane) & 1ull) != 0ull;
            double v = isc ? (fcreg[p] + cur[p] + PEN) : INFINITY;
            vals[p] = v;
            if (v < bv) { bv = v; bc = c; }   // ascending-c pass order: strict < = first occurrence
        }
        // lexicographic (val, c) butterfly argmin across 64 lanes
        #pragma unroll
        for (int off = 1; off < 64; off <<= 1) {
            double ov = __shfl_xor(bv, off);
            int oc = __shfl_xor(bc, off);
            if (ov < bv || (ov == bv && oc < bc)) { bv = ov; bc = oc; }
        }
        double thr = bv + PEN;
        if (lane == 0) prevG[b * 512 + t] = bc;
        // latch Fc[t] into the owning lane's register
        #pragma unroll
        for (int p = 0; p < 8; p++)
            if (p == (t >> 6) && lane == (t & 63)) fcreg[p] = bv;
        // prune candidates (bitmask &= keep), then add candidate t
        #pragma unroll
        for (int p = 0; p < 8; p++) {
            unsigned long long keep = __ballot(vals[p] <= thr);
            cmask[p] &= keep;
        }
        cmask[t >> 6] |= (1ull << (t & 63));
        if (t < NF) {
            #pragma unroll
            for (int p = 0; p < 8; p++) cur[p] = nxt[p];
        }
    }
}

// ---------------- fallback PELT (round-2 version) if workspace can't hold cost matrix
__global__ __launch_bounds__(64) void k_pelt_slow(const double* __restrict__ cs,
                                                  const double* __restrict__ cs2,
                                                  int* __restrict__ prevG) {
    __shared__ double sFc[512];
    __shared__ double sVal[512];
    __shared__ unsigned short sCand[512];
    int b = blockIdx.x;
    int lane = threadIdx.x;
    const double* c1 = cs + (size_t)b * 512 * NB;
    const double* c2 = cs2 + (size_t)b * 512 * NB;
    if (lane == 0) { sFc[0] = -PEN; sCand[0] = 0; }
    __syncthreads();
    int ncand = 1;
    for (int t = 1; t <= NF; t++) {
        const double* ct1 = c1 + (size_t)t * NB;
        const double* ct2 = c2 + (size_t)t * NB;
        int passes = (ncand + 63) >> 6;
        double bmv = INFINITY;
        int bmi = 0x7fffffff;
        for (int p = 0; p < passes; p++) {
            int slot = (p << 6) + lane;
            double val = INFINITY;
            if (slot < ncand) {
                int cc = sCand[slot];
                double nn = (double)(t - cc);
                const double* p1 = c1 + (size_t)cc * NB;
                const double* p2 = c2 + (size_t)cc * NB;
                double r[8];
                #pragma unroll
                for (int j = 0; j < 8; j++) {
                    double ss = ct1[j] - p1[j]; double s2 = ct2[j] - p2[j];
                    r[j] = s2 - ss * ss / nn;
                }
                #pragma unroll
                for (int base = 8; base < 32; base += 8)
                    #pragma unroll
                    for (int j = 0; j < 8; j++) {
                        int d = base + j;
                        double ss = ct1[d] - p1[d]; double s2 = ct2[d] - p2[d];
                        r[j] += s2 - ss * ss / nn;
                    }
                double res = ((r[0] + r[1]) + (r[2] + r[3])) + ((r[4] + r[5]) + (r[6] + r[7]));
                { double ss = ct1[32] - p1[32]; double s2 = ct2[32] - p2[32]; res += s2 - ss * ss / nn; }
                val = sFc[cc] + res + PEN;
                if (val < bmv) { bmv = val; bmi = slot; }
            }
            sVal[slot] = val;
        }
        #pragma unroll
        for (int off = 1; off < 64; off <<= 1) {
            double ov = __shfl_xor(bmv, off);
            int oi = __shfl_xor(bmi, off);
            if (ov < bmv || (ov == bmv && oi < bmi)) { bmv = ov; bmi = oi; }
        }
        double thr = bmv + PEN;
        if (lane == 0) {
            sFc[t] = bmv;
            prevG[b * 512 + t] = (int)sCand[bmi];
        }
        __syncthreads();
        int base = 0;
        for (int p = 0; p < passes; p++) {
            int slot = (p << 6) + lane;
            int cc = (slot < ncand) ? (int)sCand[slot] : 0;
            bool keep = (slot < ncand) && (sVal[slot] <= thr);
            unsigned long long mask = __ballot(keep);
            if (keep) sCand[base + __popcll(mask & ((1ull << lane) - 1ull))] = (unsigned short)cc;
            base += (int)__popcll(mask);
        }
        if (lane == 0) sCand[base] = (unsigned short)t;
        ncand = base + 1;
        __syncthreads();
    }
}

// ---------------- backtrack + bounds + segment table + bin offsets (1 thread per batch)
__global__ void k_bounds(const int* __restrict__ prevG, int* __restrict__ bps, int* __restrict__ bnds,
                         int* __restrict__ segS, int* __restrict__ segE, int* __restrict__ nsegA,
                         int* __restrict__ binoff) {
    int b = threadIdx.x;
    if (b >= Bn) return;
    const int* pv = prevG + b * 512;
    int* bp = bps + b * 512;
    int* bd = bnds + b * 520;
    int cnt = 0, t = NF;
    while (t > 0) { bp[cnt++] = t; t = pv[t]; }
    int nb = 1; bd[0] = 0;
    for (int i = cnt - 1; i >= 1; --i) {
        int k = bp[i];
        int bb = 32 * k;
        if (bb > Ln) bb = Ln;
        if (bb - bd[nb - 1] >= 8) bd[nb++] = bb;
    }
    if (Ln - bd[nb - 1] < 8 && nb > 1) nb--;
    bd[nb++] = Ln;
    int ns = nb - 1;
    nsegA[b] = ns;
    int off = 0;
    for (int j = 0; j < ns; j++) {
        int s = bd[j], e = bd[j + 1];
        segS[b * 512 + j] = s; segE[b * 512 + j] = e;
        binoff[b * 513 + j] = off;
        off += (e - s) >> 1;
    }
    binoff[b * 513 + ns] = off;
}

// ---------------- per-segment mean (double)
__global__ void k_segmean(const float* __restrict__ sig, const int* __restrict__ segS,
                          const int* __restrict__ segE, const int* __restrict__ nsegA,
                          double* __restrict__ segMean) {
    __shared__ double red[256];
    int b = blockIdx.y, j = blockIdx.x;
    if (j >= nsegA[b]) return;
    int s = segS[b * 512 + j], e = segE[b * 512 + j];
    double acc = 0.0;
    for (int i = s + threadIdx.x; i < e; i += 256) acc += (double)sig[b * Ln + i];
    red[threadIdx.x] = acc;
    __syncthreads();
    for (int st = 128; st >= 1; st >>= 1) {
        if (threadIdx.x < st) red[threadIdx.x] += red[threadIdx.x + st];
        __syncthreads();
    }
    if (threadIdx.x == 0) segMean[b * 512 + j] = red[0] / (double)(e - s);
}

// ---------------- segment DFT: one wave per (batch, bin-slot), rotation recurrence in double
__global__ __launch_bounds__(256) void k_spec(const float* __restrict__ sig,
                                              const double* __restrict__ segMean,
                                              const int* __restrict__ segS, const int* __restrict__ segE,
                                              const int* __restrict__ nsegA, const int* __restrict__ binoff,
                                              double* __restrict__ spec) {
    int b = blockIdx.y;
    int wv = threadIdx.x >> 6, lane = threadIdx.x & 63;
    int slot = blockIdx.x * 4 + wv;
    int ns = nsegA[b];
    const int* off = binoff + b * 513;
    if (slot >= off[ns]) return;
    int lo = 0, hi = ns - 1;
    while (lo < hi) { int mid = (lo + hi + 1) >> 1; if (off[mid] <= slot) lo = mid; else hi = mid - 1; }
    int j = lo;
    int s = segS[b * 512 + j], e = segE[b * 512 + j], n = e - s;
    int k = slot - off[j] + 1;
    float m32 = (float)segMean[b * 512 + j];
    long j0 = ((long)lane * (long)k) % (long)n;
    long js = (64L * (long)k) % (long)n;
    double a0 = (2.0 * M_PI * (double)j0) / (double)n;
    double as = (2.0 * M_PI * (double)js) / (double)n;
    double cr, sr, cb, sb;
    sincos(a0, &sr, &cr);
    sincos(as, &sb, &cb);
    double re = 0.0, im = 0.0;
    const float* sp = sig + b * Ln + s;
    for (int tt = lane; tt < n; tt += 64) {
        double v = (double)(sp[tt] - m32);
        re += v * cr;
        im += v * sr;
        double nc = cr * cb - sr * sb;
        sr = sr * cb + cr * sb;
        cr = nc;
    }
    #pragma unroll
    for (int o = 32; o >= 1; o >>= 1) { re += __shfl_down(re, o); im += __shfl_down(im, o); }
    if (lane == 0) spec[(size_t)b * TB + slot] = re * re + im * im;
}

// ---------------- per-segment stats
__global__ void k_stats(const double* __restrict__ spec, const int* __restrict__ segS,
                        const int* __restrict__ segE, const int* __restrict__ nsegA,
                        const int* __restrict__ binoff, int* __restrict__ segPL,
                        double* __restrict__ segDP, double* __restrict__ segBW,
                        int* __restrict__ segNT) {
    __shared__ double rv[256]; __shared__ int ri[256];
    __shared__ double rt[256], rs[256];
    __shared__ double sC, sTot;
    int b = blockIdx.y, j = blockIdx.x;
    if (j >= nsegA[b]) return;
    int s = segS[b * 512 + j], e = segE[b * 512 + j], n = e - s, nf = n >> 1;
    const double* base = spec + (size_t)b * TB + binoff[b * 513 + j];
    int tid = threadIdx.x;
    double mv = -INFINITY; int mi = 0x7fffffff; double tot = 0.0, s1 = 0.0;
    for (int i = tid; i < nf; i += 256) {
        double vv = base[i];
        double f = (double)(i + 1) / (double)nf;
        tot += vv; s1 += vv * f;
        if (vv > mv) { mv = vv; mi = i; }
    }
    rv[tid] = mv; ri[tid] = mi; rt[tid] = tot; rs[tid] = s1;
    __syncthreads();
    for (int st = 128; st >= 1; st >>= 1) {
        if (tid < st) {
            double ov = rv[tid + st]; int oi = ri[tid + st];
            if (ov > rv[tid] || (ov == rv[tid] && oi < ri[tid])) { rv[tid] = ov; ri[tid] = oi; }
            rt[tid] += rt[tid + st]; rs[tid] += rs[tid + st];
        }
        __syncthreads();
    }
    if (tid == 0) { sTot = rt[0]; sC = rs[0] / rt[0]; }
    __syncthreads();
    double c = sC, totv = sTot;
    double s2 = 0.0;
    for (int i = tid; i < nf; i += 256) {
        double f = (double)(i + 1) / (double)nf;
        double d = f - c;
        s2 += base[i] * d * d;
    }
    rt[tid] = s2;
    __syncthreads();
    for (int st = 128; st >= 1; st >>= 1) {
        if (tid < st) rt[tid] += rt[tid + st];
        __syncthreads();
    }
    if (tid == 0) {
        double dp, bw;
        if (n < 4) { dp = (double)(n > 0 ? n : 1); bw = 0.0; }
        else if (!(totv > 0.0)) { dp = (double)n; bw = 0.0; }
        else { int kk = ri[0] + 1; dp = (double)n / (double)kk; bw = sqrt(rt[0] / totv); }
        double raw = 1.0 * dp / (1.0 + 1.0 * bw);
        double rr = rint(raw / 2.0);          // Python round(): half-to-even
        long pl = 2L * (long)rr;
        if (pl < 8) pl = 8;
        if (pl > 64) pl = 64;
        int nfull = n / (int)pl;
        int ntok = nfull + ((nfull * (int)pl < n) ? 1 : 0);
        segPL[b * 512 + j] = (int)pl; segDP[b * 512 + j] = dp;
        segBW[b * 512 + j] = bw; segNT[b * 512 + j] = ntok;
    }
}

// ---------------- token prefix offsets per batch
__global__ void k_tokpref(const int* __restrict__ nsegA, const int* __restrict__ segNT,
                          int* __restrict__ tokoff, int* __restrict__ ntokA) {
    int b = threadIdx.x;
    if (b >= Bn) return;
    int ns = nsegA[b]; int off = 0;
    for (int j = 0; j < ns; j++) { tokoff[b * 513 + j] = off; off += segNT[b * 512 + j]; }
    tokoff[b * 513 + ns] = off;
    ntokA[b] = off;
}

// ---------------- fill all outputs: one block per (batch, token)
__global__ __launch_bounds__(256) void k_fill(const float* __restrict__ x,
                                              const int* __restrict__ segS, const int* __restrict__ segE,
                                              const int* __restrict__ segPL, const double* __restrict__ segDP,
                                              const double* __restrict__ segBW, const int* __restrict__ nsegA,
                                              const int* __restrict__ tokoff, const int* __restrict__ ntokA,
                                              float* __restrict__ out, int MT) {
    int b = blockIdx.y, tok = blockIdx.x;
    int nt = ntokA[b];
    if (tok >= nt) return;
    int ns = nsegA[b];
    const int* toff = tokoff + b * 513;
    int lo = 0, hi = ns - 1;
    while (lo < hi) { int mid = (lo + hi + 1) >> 1; if (toff[mid] <= tok) lo = mid; else hi = mid - 1; }
    int j = lo;
    int s = segS[b * 512 + j], e = segE[b * 512 + j], pl = segPL[b * 512 + j];
    int idx = tok - toff[j];
    int nfull = (e - s) / pl;
    int st, en;
    if (idx < nfull) { st = s + idx * pl; en = st + pl; }
    else { st = s + nfull * pl; en = e; }
    int ilen = en - st;
    float scale = (float)ilen / 16.0f;
    int tid = threadIdx.x;
    size_t pbase = ((size_t)(b * MT + tok)) * (Cn * 16);
    const float* xb = x + (size_t)b * Cn * Ln;
    #pragma unroll
    for (int r = 0; r < 2; r++) {
        int eidx = tid + r * 256;
        int c = eidx >> 4, jo = eidx & 15;
        float coords = ((float)jo + 0.5f) * scale - 0.5f;
        if (coords < 0.0f) coords = 0.0f;
        float mx = (float)(ilen - 1);
        if (coords > mx) coords = mx;
        int l2 = (int)floorf(coords);
        int h2 = l2 + 1;
        if (h2 > ilen - 1) h2 = ilen - 1;
        float w = coords - (float)l2;
        const float* xc = xb + (size_t)c * Ln + st;
        out[pbase + eidx] = xc[l2] * (1.0f - w) + xc[h2] * w;
    }
    if (tid == 0) {
        size_t BT = (size_t)Bn * MT;
        size_t o_mask = BT * 512;
        size_t pos = (size_t)b * MT + tok;
        out[o_mask + pos] = 1.0f;                                  // mask
        out[o_mask + BT + pos] = (float)st;                        // start
        out[o_mask + 2 * BT + pos] = (float)en;                    // end
        out[o_mask + 3 * BT + pos] = (((float)st + (float)en) - 1.0f) * 0.5f / 16383.0f;  // center
        out[o_mask + 4 * BT + pos] = (float)(en - st) / 16384.0f;  // span
        double dp = segDP[b * 512 + j], bwv = segBW[b * 512 + j];
        size_t o_rg = o_mask + 5 * BT;
        out[o_rg + pos * 3 + 0] = (float)(dp / 16384.0);
        out[o_rg + pos * 3 + 1] = (float)bwv;
        out[o_rg + pos * 3 + 2] = (float)((double)(e - s) / 16384.0);
        if (tok == 0) out[o_mask + 8 * BT + b] = (float)nt;        // n_tok
    }
}

extern "C" void kernel_launch(void* const* d_in, const int* in_sizes, int n_in,
                              void* d_out, int out_size, void* d_ws, size_t ws_size,
                              hipStream_t stream) {
    (void)in_sizes; (void)n_in;
    const float* x = (const float*)d_in[0];
    float* out = (float*)d_out;
    char* ws = (char*)d_ws;
    size_t o = 0;
    auto alloc = [&](size_t bytes) -> char* {
        char* r = ws + o;
        o = (o + bytes + 511) & ~(size_t)511;
        return r;
    };
    float* sig = (float*)alloc((size_t)Bn * Ln * 4);
    float* fm = (float*)alloc((size_t)Bn * NF * 4);
    double* feats = (double*)alloc((size_t)Bn * NF * NB * 8);
    double* cs = (double*)alloc((size_t)Bn * 512 * NB * 8);
    double* cs2 = (double*)alloc((size_t)Bn * 512 * NB * 8);
    int* prevG = (int*)alloc((size_t)Bn * 512 * 4);
    int* bps = (int*)alloc((size_t)Bn * 512 * 4);
    int* bnds = (int*)alloc((size_t)Bn * 520 * 4);
    int* nsegA = (int*)alloc((size_t)Bn * 4);
    int* segS = (int*)alloc((size_t)Bn * 512 * 4);
    int* segE = (int*)alloc((size_t)Bn * 512 * 4);
    int* segPL = (int*)alloc((size_t)Bn * 512 * 4);
    int* segNT = (int*)alloc((size_t)Bn * 512 * 4);
    double* segDP = (double*)alloc((size_t)Bn * 512 * 8);
    double* segBW = (double*)alloc((size_t)Bn * 512 * 8);
    double* segMean = (double*)alloc((size_t)Bn * 512 * 8);
    int* binoff = (int*)alloc((size_t)Bn * 513 * 4);
    int* tokoff = (int*)alloc((size_t)Bn * 513 * 4);
    int* ntokA = (int*)alloc((size_t)Bn * 4);
    double* spec = (double*)alloc((size_t)Bn * TB * 8);
    size_t costBytes = (size_t)Bn * 512 * 512 * 8;   // 67 MB
    double* costM = (double*)alloc(costBytes);
    bool haveCost = (o <= ws_size);

    int MT = (out_size / Bn - 1) / 520;   // out_size = Bn*(MT*520 + 1)

    hipMemsetAsync(d_out, 0, (size_t)out_size * 4, stream);
    k_sig<<<(Bn * Ln + 255) / 256, 256, 0, stream>>>(x, sig);
    k_fmean<<<(Bn * NF + 255) / 256, 256, 0, stream>>>(sig, fm);
    k_feats<<<Bn * NF, 64, 0, stream>>>(sig, fm, feats);
    k_cumsum<<<(Bn * NB + 255) / 256, 256, 0, stream>>>(feats, cs, cs2);
    if (haveCost) {
        k_cost<<<dim3(NF, Bn), 256, 0, stream>>>(cs, cs2, costM);
        k_pelt<<<Bn, 64, 0, stream>>>(costM, prevG);
    } else {
        k_pelt_slow<<<Bn, 64, 0, stream>>>(cs, cs2, prevG);
    }
    k_bounds<<<1, 32, 0, stream>>>(prevG, bps, bnds, segS, segE, nsegA, binoff);
    k_segmean<<<dim3(MAXSEG, Bn), 256, 0, stream>>>(sig, segS, segE, nsegA, segMean);
    k_spec<<<dim3(TB / 4, Bn), 256, 0, stream>>>(sig, segMean, segS, segE, nsegA, binoff, spec);
    k_stats<<<dim3(MAXSEG, Bn), 256, 0, stream>>>(spec, segS, segE, nsegA, binoff,
                                                  segPL, segDP, segBW, segNT);
    k_tokpref<<<1, 32, 0, stream>>>(nsegA, segNT, tokoff, ntokA);
    if (MT > 0)
        k_fill<<<dim3(MT, Bn), 256, 0, stream>>>(x, segS, segE, segPL, segDP, segBW,
                                                 nsegA, tokoff, ntokA, out, MT);
}